// Round 5
// baseline (516.190 us; speedup 1.0000x reference)
//
#include <hip/hip_runtime.h>
#include <cstdint>
#include <cstddef>

#define KNN 16
#define NPTS 256
#define NBATCH 128

static constexpr float BN_SCALE_F = 0.9999950000374997f; // 1/sqrt(1+1e-5)

__device__ inline unsigned int f32_ord(float f) {
    unsigned int u = __float_as_uint(f);
    return (u & 0x80000000u) ? ~u : (u | 0x80000000u);
}

// ---------------------------------------------------------------------------
// sq[t] = sum_d x[t][d]^2, sequential fmaf chain (matches reference assoc).
// ---------------------------------------------------------------------------
template<int D>
__global__ __launch_bounds__(256) void sq_kernel(const float* __restrict__ x,
                                                 float* __restrict__ sq) {
    const int t = blockIdx.x * 256 + threadIdx.x;
    const float* r = x + (size_t)t * D;
    float s = 0.f;
    #pragma unroll
    for (int d = 0; d < D; ++d) s = fmaf(r[d], r[d], s);
    sq[t] = s;
}

// ---------------------------------------------------------------------------
// Distance GEMM v2: d2[b][i][j] = (sq_i + sq_j) - 2*dot, diag=+INF.
// 128x128 tile / 128 threads (2 waves), 16x8 per-thread tile.
// As (row operand) uses gapped layout col(m)=m+4*(m>>4), stride 160
//   -> the 8 distinct ty8*20 fragment addresses cover all 8 bank-quads
//   -> conflict-free b128 reads.  Bs stride 132 -> 2-way (free).
// Per kk: 6 b128 + 128 FMA  (was 4 b128 / 64 FMA -> LDS-pipe-bound).
// dot accumulates ascending d -> d2 bit-identical to rounds 1-4.
// ---------------------------------------------------------------------------
template<int D>
__global__ __launch_bounds__(128) void gram_kernel(const float* __restrict__ x,
                                                   const float* __restrict__ sq,
                                                   float* __restrict__ d2) {
    constexpr int KT = (D >= 16) ? 16 : D;
    const int t = threadIdx.x;
    const int w = t >> 6, l = t & 63;
    const int tx8 = l & 7, ty8 = l >> 3;
    const int rowL = ty8 * 16;
    const int colL = w * 64 + tx8 * 8;
    const int b    = blockIdx.x >> 2;
    const int tile = blockIdx.x & 3;
    const int i0 = (tile & 1) * 128;
    const int j0 = (tile >> 1) * 128;
    const int base = b * NPTS;

    __shared__ float As[KT][160];   // gapped: col(m) = m + 4*(m>>4)
    __shared__ float Bs[KT][132];

    float acc[16][8] = {};
    for (int k0 = 0; k0 < D; k0 += KT) {
        if constexpr (D % 16 == 0) {
            const float* pa = x + (size_t)(base + i0 + t) * D + k0;
            const float* pb = x + (size_t)(base + j0 + t) * D + k0;
            const int ca = t + 4 * (t >> 4);
            #pragma unroll
            for (int q = 0; q < 4; ++q) {
                const float4 v = *(const float4*)(pa + q * 4);
                As[q*4+0][ca] = v.x; As[q*4+1][ca] = v.y;
                As[q*4+2][ca] = v.z; As[q*4+3][ca] = v.w;
            }
            #pragma unroll
            for (int q = 0; q < 4; ++q) {
                const float4 v = *(const float4*)(pb + q * 4);
                Bs[q*4+0][t] = v.x; Bs[q*4+1][t] = v.y;
                Bs[q*4+2][t] = v.z; Bs[q*4+3][t] = v.w;
            }
        } else {
            for (int e = t; e < 128 * KT; e += 128) {
                const int r = e / KT, c = e % KT;
                As[c][r + 4 * (r >> 4)] = x[(size_t)(base + i0 + r) * D + k0 + c];
                Bs[c][r]                = x[(size_t)(base + j0 + r) * D + k0 + c];
            }
        }
        __syncthreads();
        const int ra = ty8 * 20;
        #pragma unroll
        for (int kk = 0; kk < KT; ++kk) {
            float am[16], bm[8];
            *(float4*)&am[0]  = *(const float4*)&As[kk][ra];
            *(float4*)&am[4]  = *(const float4*)&As[kk][ra + 4];
            *(float4*)&am[8]  = *(const float4*)&As[kk][ra + 8];
            *(float4*)&am[12] = *(const float4*)&As[kk][ra + 12];
            *(float4*)&bm[0]  = *(const float4*)&Bs[kk][colL];
            *(float4*)&bm[4]  = *(const float4*)&Bs[kk][colL + 4];
            #pragma unroll
            for (int m = 0; m < 16; ++m)
                #pragma unroll
                for (int n = 0; n < 8; ++n)
                    acc[m][n] = fmaf(am[m], bm[n], acc[m][n]);
        }
        __syncthreads();
    }

    float sqj[8];
    #pragma unroll
    for (int n = 0; n < 8; ++n) sqj[n] = sq[base + j0 + colL + n];
    #pragma unroll
    for (int m = 0; m < 16; ++m) {
        const int gi = i0 + rowL + m;
        const float sqi = sq[base + gi];
        float v[8];
        #pragma unroll
        for (int n = 0; n < 8; ++n) {
            v[n] = (sqi + sqj[n]) - 2.f * acc[m][n];
            if (gi == j0 + colL + n) v[n] = INFINITY;
        }
        float* dst = d2 + ((size_t)b << 16) + (size_t)gi * NPTS + j0 + colL;
        *(float4*)(dst)     = make_float4(v[0], v[1], v[2], v[3]);
        *(float4*)(dst + 4) = make_float4(v[4], v[5], v[6], v[7]);
    }
}

// ---------------------------------------------------------------------------
// Top-16 selection, pure VALU (unchanged from r3).
// ---------------------------------------------------------------------------
__global__ __launch_bounds__(256) void topk_kernel(const float* __restrict__ d2,
                                                   int* __restrict__ idx) {
    const int t = threadIdx.x;
    const int p = t >> 3;
    const int q = t & 7;
    const int ig = blockIdx.x * 32 + p;
    const float* row = d2 + (size_t)ig * NPTS;

    unsigned long long L[16];
    #pragma unroll
    for (int r = 0; r < 16; ++r) L[r] = ~0ull;

    const int jb = q * 32;
    #pragma unroll
    for (int jj = 0; jj < 32; jj += 4) {
        const float4 v4 = *(const float4*)(row + jb + jj);
        const float vv[4] = {v4.x, v4.y, v4.z, v4.w};
        #pragma unroll
        for (int e = 0; e < 4; ++e) {
            const unsigned long long key =
                ((unsigned long long)f32_ord(vv[e]) << 32) |
                (unsigned int)(jb + jj + e);
            #pragma unroll
            for (int r = 15; r >= 1; --r)
                L[r] = (key < L[r]) ? ((key < L[r - 1]) ? L[r - 1] : key) : L[r];
            L[0] = (key < L[0]) ? key : L[0];
        }
    }

    __shared__ unsigned long long K[256][17];
    #pragma unroll
    for (int r = 0; r < 16; ++r) K[t][r] = L[r];
    __syncthreads();

    if (t < 32) {
        const int pp  = t;
        const int igo = blockIdx.x * 32 + pp;
        int h[8];
        unsigned long long v[8];
        #pragma unroll
        for (int c = 0; c < 8; ++c) { h[c] = 0; v[c] = K[pp * 8 + c][0]; }
        int outj[16];
        #pragma unroll
        for (int r = 0; r < 16; ++r) {
            unsigned long long best = v[0];
            #pragma unroll
            for (int c = 1; c < 8; ++c) best = (v[c] < best) ? v[c] : best;
            outj[r] = (int)(unsigned int)(best & 0xffffffffull);
            #pragma unroll
            for (int c = 0; c < 8; ++c) {
                const bool hit = (v[c] == best);
                const int hn = h[c] + (hit ? 1 : 0);
                const unsigned long long nv = K[pp * 8 + c][hn & 15];
                v[c] = hit ? ((hn < 16) ? nv : ~0ull) : v[c];
                h[c] = hn;
            }
        }
        int4* op = (int4*)(idx + (size_t)igo * KNN);
        op[0] = make_int4(outj[0],  outj[1],  outj[2],  outj[3]);
        op[1] = make_int4(outj[4],  outj[5],  outj[6],  outj[7]);
        op[2] = make_int4(outj[8],  outj[9],  outj[10], outj[11]);
        op[3] = make_int4(outj[12], outj[13], outj[14], outj[15]);
    }
}

// ---------------------------------------------------------------------------
// Factorized edge-MLP GEMM v2: X (M x D) @ W' (D x 2C), same math as r4
// (W'[:,0:C)=Wt-Wb formed at staging; ascending-d fmaf chain -> bit-exact).
// 128x128 tile / 128 threads, 16x8 per-thread, gapped Xs layout (see gram).
// Epilogue: A = gc*U ; Bv = gc*(V + b) + be.
// ---------------------------------------------------------------------------
template<int D, int C>
__global__ __launch_bounds__(128) void mlp_gemm_kernel(
        const float* __restrict__ x, const float* __restrict__ W,
        const float* __restrict__ bias, const float* __restrict__ g,
        const float* __restrict__ be,
        float* __restrict__ A, float* __restrict__ Bv) {
    constexpr int KT = (D >= 16) ? 16 : D;
    const int t = threadIdx.x;
    const int w = t >> 6, l = t & 63;
    const int tx8 = l & 7, ty8 = l >> 3;
    const int colL = w * 64 + tx8 * 8;
    const int m0 = blockIdx.x * 128;
    const int n0 = blockIdx.y * 128;

    __shared__ float Xs[KT][160];   // gapped: col(m) = m + 4*(m>>4)
    __shared__ float Ws[KT][132];

    float acc[16][8] = {};
    for (int k0 = 0; k0 < D; k0 += KT) {
        if constexpr (D % 16 == 0) {
            // ---- stage X tile (128 rows x KT), gapped-transposed ----
            const float* px = x + (size_t)(m0 + t) * D + k0;
            const int ca = t + 4 * (t >> 4);
            #pragma unroll
            for (int q = 0; q < 4; ++q) {
                const float4 v = *(const float4*)(px + q * 4);
                Xs[q*4+0][ca] = v.x; Xs[q*4+1][ca] = v.y;
                Xs[q*4+2][ca] = v.z; Xs[q*4+3][ca] = v.w;
            }
            // ---- stage W' tile (KT x 128) ----
            const int wk = t & 15, nq = (t >> 4) * 16;
            const int gn = n0 + nq, kr = k0 + wk;
            if (gn < C) {
                const float* pt = W + (size_t)kr * C + gn;
                const float* pb = W + (size_t)(D + kr) * C + gn;
                #pragma unroll
                for (int q = 0; q < 4; ++q) {
                    const float4 a4 = *(const float4*)(pt + q * 4);
                    const float4 b4 = *(const float4*)(pb + q * 4);
                    Ws[wk][nq+q*4+0] = a4.x - b4.x;
                    Ws[wk][nq+q*4+1] = a4.y - b4.y;
                    Ws[wk][nq+q*4+2] = a4.z - b4.z;
                    Ws[wk][nq+q*4+3] = a4.w - b4.w;
                }
            } else {
                const float* pb = W + (size_t)(D + kr) * C + (gn - C);
                #pragma unroll
                for (int q = 0; q < 4; ++q) {
                    const float4 b4 = *(const float4*)(pb + q * 4);
                    Ws[wk][nq+q*4+0] = b4.x; Ws[wk][nq+q*4+1] = b4.y;
                    Ws[wk][nq+q*4+2] = b4.z; Ws[wk][nq+q*4+3] = b4.w;
                }
            }
        } else {
            for (int e = t; e < 128 * KT; e += 128) {
                const int r = e / KT, c = e % KT;
                Xs[c][r + 4 * (r >> 4)] = x[(size_t)(m0 + r) * D + k0 + c];
            }
            for (int e = t; e < KT * 128; e += 128) {
                const int c = e >> 7, n = e & 127;
                const int gn = n0 + n, kr = k0 + c;
                Ws[c][n] = (gn < C)
                    ? W[(size_t)kr * C + gn] - W[(size_t)(D + kr) * C + gn]
                    : W[(size_t)(D + kr) * C + (gn - C)];
            }
        }
        __syncthreads();
        const int ra = ty8 * 20;
        #pragma unroll
        for (int kk = 0; kk < KT; ++kk) {
            float xm[16], wn[8];
            *(float4*)&xm[0]  = *(const float4*)&Xs[kk][ra];
            *(float4*)&xm[4]  = *(const float4*)&Xs[kk][ra + 4];
            *(float4*)&xm[8]  = *(const float4*)&Xs[kk][ra + 8];
            *(float4*)&xm[12] = *(const float4*)&Xs[kk][ra + 12];
            *(float4*)&wn[0]  = *(const float4*)&Ws[kk][colL];
            *(float4*)&wn[4]  = *(const float4*)&Ws[kk][colL + 4];
            #pragma unroll
            for (int m = 0; m < 16; ++m)
                #pragma unroll
                for (int n = 0; n < 8; ++n)
                    acc[m][n] = fmaf(xm[m], wn[n], acc[m][n]);
        }
        __syncthreads();
    }

    // ---- epilogue: affine + route halves (8-col blocks never straddle C) ----
    const int gn = n0 + colL;
    if (gn < C) {
        float fac[8];
        #pragma unroll
        for (int e = 0; e < 8; ++e) fac[e] = g[gn + e] * BN_SCALE_F;
        #pragma unroll
        for (int m = 0; m < 16; ++m) {
            float o[8];
            #pragma unroll
            for (int e = 0; e < 8; ++e) o[e] = fac[e] * acc[m][e];
            float* dst = A + (size_t)(m0 + ty8 * 16 + m) * C + gn;
            *(float4*)(dst)     = make_float4(o[0], o[1], o[2], o[3]);
            *(float4*)(dst + 4) = make_float4(o[4], o[5], o[6], o[7]);
        }
    } else {
        const int cb = gn - C;
        float fac[8], bb[8], bee[8];
        #pragma unroll
        for (int e = 0; e < 8; ++e) {
            fac[e] = g[cb + e] * BN_SCALE_F;
            bb[e]  = bias[cb + e];
            bee[e] = be[cb + e];
        }
        #pragma unroll
        for (int m = 0; m < 16; ++m) {
            float o[8];
            #pragma unroll
            for (int e = 0; e < 8; ++e)
                o[e] = fmaf(fac[e], acc[m][e] + bb[e], bee[e]);
            float* dst = Bv + (size_t)(m0 + ty8 * 16 + m) * C + cb;
            *(float4*)(dst)     = make_float4(o[0], o[1], o[2], o[3]);
            *(float4*)(dst + 4) = make_float4(o[4], o[5], o[6], o[7]);
        }
    }
}

// ---------------------------------------------------------------------------
// Combine: out[i][c] = relu(A[i][c] + max_{j in knn(i)} Bv[j][c]). out aliases A.
// ---------------------------------------------------------------------------
template<int C>
__global__ __launch_bounds__(C) void combine_kernel(
        const float* A, const float* __restrict__ Bv,
        const int* __restrict__ idx, float* out) {
    const int bi = blockIdx.x;
    const int c  = threadIdx.x;
    __shared__ int nbr[KNN];
    if (c < KNN) nbr[c] = idx[(size_t)bi * KNN + c];
    __syncthreads();
    const int b0 = bi & ~255;
    float mx = -INFINITY;
    #pragma unroll
    for (int kk = 0; kk < KNN; ++kk)
        mx = fmaxf(mx, Bv[(size_t)(b0 + nbr[kk]) * C + c]);
    float a = A[(size_t)bi * C + c];
    out[(size_t)bi * C + c] = fmaxf(a + mx, 0.f);
}

// ---------------------------------------------------------------------------
// Head: global max-pool over N, then 2 tiny FCs. One block per batch.
// ---------------------------------------------------------------------------
__global__ __launch_bounds__(256) void head_kernel(
        const float* __restrict__ h3, const float* __restrict__ Wf1,
        const float* __restrict__ bf1, const float* __restrict__ gf,
        const float* __restrict__ bef, const float* __restrict__ Wf2,
        const float* __restrict__ bf2, float* __restrict__ out) {
    const int b   = blockIdx.x;
    const int tid = threadIdx.x;
    __shared__ float p[256];
    __shared__ float f[128];
    const float* hb = h3 + (size_t)b * NPTS * 256;
    float mx = -INFINITY;
    for (int n = 0; n < NPTS; ++n) mx = fmaxf(mx, hb[(size_t)n * 256 + tid]);
    p[tid] = mx;
    __syncthreads();
    if (tid < 128) {
        float acc = bf1[tid];
        for (int d = 0; d < 256; ++d)
            acc = fmaf(p[d], Wf1[(size_t)d * 128 + tid], acc);
        float v = gf[tid] * (acc * BN_SCALE_F) + bef[tid];
        f[tid] = fmaxf(v, 0.f);
    }
    __syncthreads();
    if (tid < 12) {
        float acc = bf2[tid];
        for (int d = 0; d < 128; ++d)
            acc = fmaf(f[d], Wf2[(size_t)d * 12 + tid], acc);
        out[(size_t)b * 12 + tid] = acc;
    }
}

extern "C" void kernel_launch(void* const* d_in, const int* in_sizes, int n_in,
                              void* d_out, int out_size, void* d_ws, size_t ws_size,
                              hipStream_t stream) {
    const float* x   = (const float*)d_in[0];
    const float* W1  = (const float*)d_in[1];
    const float* b1  = (const float*)d_in[2];
    const float* g1  = (const float*)d_in[3];
    const float* be1 = (const float*)d_in[4];
    const float* W2  = (const float*)d_in[5];
    const float* b2  = (const float*)d_in[6];
    const float* g2  = (const float*)d_in[7];
    const float* be2 = (const float*)d_in[8];
    const float* W3  = (const float*)d_in[9];
    const float* b3  = (const float*)d_in[10];
    const float* g3  = (const float*)d_in[11];
    const float* be3 = (const float*)d_in[12];
    const float* Wf1 = (const float*)d_in[13];
    const float* bf1 = (const float*)d_in[14];
    const float* gf  = (const float*)d_in[15];
    const float* bef = (const float*)d_in[16];
    const float* Wf2 = (const float*)d_in[17];
    const float* bf2 = (const float*)d_in[18];
    float* out = (float*)d_out;

    char* ws = (char*)d_ws;
    const size_t idx_bytes = (size_t)NBATCH * NPTS * KNN * sizeof(int);   // 2 MB
    const size_t reg_bytes = (size_t)NBATCH * NPTS * 256 * sizeof(float); // 32 MB
    int*   idx = (int*)ws;
    float* R1  = (float*)(ws + idx_bytes);
    float* R2  = (float*)(ws + idx_bytes + reg_bytes);
    float* R3  = (float*)(ws + idx_bytes + 2 * reg_bytes);
    float* sqb = (float*)(ws + idx_bytes + 3 * reg_bytes);                // 128 KB

    const int BN = NBATCH * NPTS;        // 32768 points
    const int GRAM_GRID = NBATCH * 4;    // 512 blocks of 128 threads
    const int TOPK_GRID = BN / 32;       // 1024 blocks
    const int MB = BN / 128;             // 256 m-blocks for the MLP GEMM

    // ---- Layer 1: x (D=6) -> h1 (C=64) in R1; d2 scratch = R3 ----
    sq_kernel<6><<<BN / 256, 256, 0, stream>>>(x, sqb);
    gram_kernel<6><<<GRAM_GRID, 128, 0, stream>>>(x, sqb, R3);
    topk_kernel<<<TOPK_GRID, 256, 0, stream>>>(R3, idx);
    mlp_gemm_kernel<6, 64><<<dim3(MB, 1), 128, 0, stream>>>(
        x, W1, b1, g1, be1, R1, R2);
    combine_kernel<64><<<BN, 64, 0, stream>>>(R1, R2, idx, R1);   // h1 = R1

    // ---- Layer 2: h1 (D=64) -> h2 (C=128) in R2; d2 scratch = R3 ----
    sq_kernel<64><<<BN / 256, 256, 0, stream>>>(R1, sqb);
    gram_kernel<64><<<GRAM_GRID, 128, 0, stream>>>(R1, sqb, R3);
    topk_kernel<<<TOPK_GRID, 256, 0, stream>>>(R3, idx);
    mlp_gemm_kernel<64, 128><<<dim3(MB, 2), 128, 0, stream>>>(
        R1, W2, b2, g2, be2, R2, R3);
    combine_kernel<128><<<BN, 128, 0, stream>>>(R2, R3, idx, R2); // h2 = R2

    // ---- Layer 3: h2 (D=128) -> h3 (C=256) in R3; d2 scratch = R1 ----
    sq_kernel<128><<<BN / 256, 256, 0, stream>>>(R2, sqb);
    gram_kernel<128><<<GRAM_GRID, 128, 0, stream>>>(R2, sqb, R1);
    topk_kernel<<<TOPK_GRID, 256, 0, stream>>>(R1, idx);
    mlp_gemm_kernel<128, 256><<<dim3(MB, 4), 128, 0, stream>>>(
        R2, W3, b3, g3, be3, R3, R1);
    combine_kernel<256><<<BN, 256, 0, stream>>>(R3, R1, idx, R3); // h3 = R3

    // ---- Head ----
    head_kernel<<<NBATCH, 256, 0, stream>>>(R3, Wf1, bf1, gf, bef, Wf2, bf2, out);
}

// Round 6
// 482.081 us; speedup vs baseline: 1.0708x; 1.0708x over previous
//
#include <hip/hip_runtime.h>
#include <cstdint>
#include <cstddef>

#define KNN 16
#define NPTS 256
#define NBATCH 128

static constexpr float BN_SCALE_F = 0.9999950000374997f; // 1/sqrt(1+1e-5)

__device__ inline unsigned int f32_ord(float f) {
    unsigned int u = __float_as_uint(f);
    return (u & 0x80000000u) ? ~u : (u | 0x80000000u);
}

// Ws column gap map: stride 160 (=0 mod 32); 16-blocks shifted by 4 banks.
__device__ __forceinline__ int wmap(int n) { return n + 4 * (n >> 4); }

// ---------------------------------------------------------------------------
// sq[t] = sum_d x[t][d]^2, sequential fmaf chain (matches reference assoc).
// ---------------------------------------------------------------------------
template<int D>
__global__ __launch_bounds__(256) void sq_kernel(const float* __restrict__ x,
                                                 float* __restrict__ sq) {
    const int t = blockIdx.x * 256 + threadIdx.x;
    const float* r = x + (size_t)t * D;
    float s = 0.f;
    #pragma unroll
    for (int d = 0; d < D; ++d) s = fmaf(r[d], r[d], s);
    sq[t] = s;
}

// ---------------------------------------------------------------------------
// Distance GEMM (r4 version — conflict-clean): d2 = (sq_i+sq_j) - 2*dot,
// diag=+INF. 64x64 tile / 256 threads, 4x4 per thread.
// ---------------------------------------------------------------------------
template<int D>
__global__ __launch_bounds__(256) void gram_kernel(const float* __restrict__ x,
                                                   const float* __restrict__ sq,
                                                   float* __restrict__ d2) {
    constexpr int KS = (D >= 16) ? 16 : D;
    const int t  = threadIdx.x;
    const int tx = t & 15, ty = t >> 4;
    const int b    = blockIdx.x >> 4;
    const int tile = blockIdx.x & 15;
    const int i0 = (tile & 3) * 64;
    const int j0 = (tile >> 2) * 64;
    const int base = b * NPTS;

    __shared__ float As[KS][68];
    __shared__ float Bs[KS][68];

    float acc[4][4] = {};
    for (int k0 = 0; k0 < D; k0 += KS) {
        if constexpr (D % 16 == 0) {
            const int r  = t >> 2;
            const int cq = (t & 3) * 4;
            const float4 va = *(const float4*)(x + (size_t)(base + i0 + r) * D + k0 + cq);
            const float4 vb = *(const float4*)(x + (size_t)(base + j0 + r) * D + k0 + cq);
            As[cq + 0][r] = va.x; As[cq + 1][r] = va.y;
            As[cq + 2][r] = va.z; As[cq + 3][r] = va.w;
            Bs[cq + 0][r] = vb.x; Bs[cq + 1][r] = vb.y;
            Bs[cq + 2][r] = vb.z; Bs[cq + 3][r] = vb.w;
        } else {
            for (int e = t; e < 64 * KS; e += 256) {
                const int r = e / KS, c = e % KS;
                As[c][r] = x[(size_t)(base + i0 + r) * D + k0 + c];
                Bs[c][r] = x[(size_t)(base + j0 + r) * D + k0 + c];
            }
        }
        __syncthreads();
        #pragma unroll
        for (int kk = 0; kk < KS; ++kk) {
            const float4 av = *(const float4*)&As[kk][ty * 4];
            const float4 bv = *(const float4*)&Bs[kk][tx * 4];
            const float am[4] = {av.x, av.y, av.z, av.w};
            const float bm[4] = {bv.x, bv.y, bv.z, bv.w};
            #pragma unroll
            for (int m = 0; m < 4; ++m)
                #pragma unroll
                for (int n = 0; n < 4; ++n)
                    acc[m][n] = fmaf(am[m], bm[n], acc[m][n]);
        }
        __syncthreads();
    }

    float sqi[4], sqj[4];
    #pragma unroll
    for (int m = 0; m < 4; ++m) {
        sqi[m] = sq[base + i0 + ty * 4 + m];
        sqj[m] = sq[base + j0 + tx * 4 + m];
    }
    #pragma unroll
    for (int m = 0; m < 4; ++m) {
        const int gi = i0 + ty * 4 + m;
        float v[4];
        #pragma unroll
        for (int n = 0; n < 4; ++n) {
            v[n] = (sqi[m] + sqj[n]) - 2.f * acc[m][n];
            if (gi == j0 + tx * 4 + n) v[n] = INFINITY;
        }
        float4* dst = (float4*)(d2 + ((size_t)b << 16) + (size_t)gi * NPTS + j0 + tx * 4);
        *dst = make_float4(v[0], v[1], v[2], v[3]);
    }
}

// ---------------------------------------------------------------------------
// Top-16 selection, pure VALU (unchanged from r3).
// ---------------------------------------------------------------------------
__global__ __launch_bounds__(256) void topk_kernel(const float* __restrict__ d2,
                                                   int* __restrict__ idx) {
    const int t = threadIdx.x;
    const int p = t >> 3;
    const int q = t & 7;
    const int ig = blockIdx.x * 32 + p;
    const float* row = d2 + (size_t)ig * NPTS;

    unsigned long long L[16];
    #pragma unroll
    for (int r = 0; r < 16; ++r) L[r] = ~0ull;

    const int jb = q * 32;
    #pragma unroll
    for (int jj = 0; jj < 32; jj += 4) {
        const float4 v4 = *(const float4*)(row + jb + jj);
        const float vv[4] = {v4.x, v4.y, v4.z, v4.w};
        #pragma unroll
        for (int e = 0; e < 4; ++e) {
            const unsigned long long key =
                ((unsigned long long)f32_ord(vv[e]) << 32) |
                (unsigned int)(jb + jj + e);
            #pragma unroll
            for (int r = 15; r >= 1; --r)
                L[r] = (key < L[r]) ? ((key < L[r - 1]) ? L[r - 1] : key) : L[r];
            L[0] = (key < L[0]) ? key : L[0];
        }
    }

    __shared__ unsigned long long K[256][17];
    #pragma unroll
    for (int r = 0; r < 16; ++r) K[t][r] = L[r];
    __syncthreads();

    if (t < 32) {
        const int pp  = t;
        const int igo = blockIdx.x * 32 + pp;
        int h[8];
        unsigned long long v[8];
        #pragma unroll
        for (int c = 0; c < 8; ++c) { h[c] = 0; v[c] = K[pp * 8 + c][0]; }
        int outj[16];
        #pragma unroll
        for (int r = 0; r < 16; ++r) {
            unsigned long long best = v[0];
            #pragma unroll
            for (int c = 1; c < 8; ++c) best = (v[c] < best) ? v[c] : best;
            outj[r] = (int)(unsigned int)(best & 0xffffffffull);
            #pragma unroll
            for (int c = 0; c < 8; ++c) {
                const bool hit = (v[c] == best);
                const int hn = h[c] + (hit ? 1 : 0);
                const unsigned long long nv = K[pp * 8 + c][hn & 15];
                v[c] = hit ? ((hn < 16) ? nv : ~0ull) : v[c];
                h[c] = hn;
            }
        }
        int4* op = (int4*)(idx + (size_t)igo * KNN);
        op[0] = make_int4(outj[0],  outj[1],  outj[2],  outj[3]);
        op[1] = make_int4(outj[4],  outj[5],  outj[6],  outj[7]);
        op[2] = make_int4(outj[8],  outj[9],  outj[10], outj[11]);
        op[3] = make_int4(outj[12], outj[13], outj[14], outj[15]);
    }
}

// ---------------------------------------------------------------------------
// Factorized edge-MLP GEMM (r4 structure + gapped Ws): X (M x D) @ W' (D x 2C),
//   W'[:,0:C)=Wt-Wb (formed at staging), W'[:,C:2C)=Wb; ascending-d fmaf
//   chain -> bit-exact vs rounds 1-5.
// 256 threads, 128x128 block tile, 8x8 per-thread tile.
// Ws uses gap map wmap(n)=n+4*(n>>4), stride 160: the 16 tx*8 fragment
// addresses land pairwise on 8 bank-quads -> 2-way (free) instead of 4-way.
// ---------------------------------------------------------------------------
template<int D, int C>
__global__ __launch_bounds__(256) void mlp_gemm_kernel(
        const float* __restrict__ x, const float* __restrict__ W,
        const float* __restrict__ bias, const float* __restrict__ g,
        const float* __restrict__ be,
        float* __restrict__ A, float* __restrict__ Bv) {
    constexpr int BM = 128;
    constexpr int KT = (D >= 16) ? 16 : D;
    const int t  = threadIdx.x;
    const int m0 = blockIdx.x * BM;
    const int n0 = blockIdx.y * 128;
    const int tx = t & 15;   // col group (8 cols)
    const int ty = t >> 4;   // row group (8 rows)

    __shared__ float Xs[KT][BM + 4];
    __shared__ float Ws[KT][160];      // gapped columns via wmap()

    float acc[8][8] = {};

    for (int k0 = 0; k0 < D; k0 += KT) {
        // ---- stage X tile (BM x KT), transposed to [k][m] ----
        if constexpr (D % 16 == 0) {
            const int r  = t >> 1;          // 0..127
            const int cq = (t & 1) * 8;     // 0 or 8
            const float* src = x + (size_t)(m0 + r) * D + k0 + cq;
            const float4 v0 = *(const float4*)(src);
            const float4 v1 = *(const float4*)(src + 4);
            Xs[cq + 0][r] = v0.x; Xs[cq + 1][r] = v0.y;
            Xs[cq + 2][r] = v0.z; Xs[cq + 3][r] = v0.w;
            Xs[cq + 4][r] = v1.x; Xs[cq + 5][r] = v1.y;
            Xs[cq + 6][r] = v1.z; Xs[cq + 7][r] = v1.w;
        } else {
            for (int e = t; e < BM * KT; e += 256) {
                const int r = e / KT, c = e % KT;
                Xs[c][r] = x[(size_t)(m0 + r) * D + k0 + c];
            }
        }
        // ---- stage W' tile (KT x 128) into gapped layout ----
        if constexpr (D % 16 == 0) {
            const int wk = t >> 4;           // 0..15 (k row)
            const int nq = (t & 15) * 8;     // col offset (8-block)
            const int mb = wmap(nq);         // mapped col base (contiguous 8)
            const int gn = n0 + nq;
            const int kr = k0 + wk;
            if (gn < C) {
                const float* pt = W + (size_t)kr * C + gn;
                const float* pb = W + (size_t)(D + kr) * C + gn;
                const float4 t0 = *(const float4*)(pt);
                const float4 t1 = *(const float4*)(pt + 4);
                const float4 b0 = *(const float4*)(pb);
                const float4 b1 = *(const float4*)(pb + 4);
                *(float4*)&Ws[wk][mb]     = make_float4(t0.x - b0.x, t0.y - b0.y,
                                                        t0.z - b0.z, t0.w - b0.w);
                *(float4*)&Ws[wk][mb + 4] = make_float4(t1.x - b1.x, t1.y - b1.y,
                                                        t1.z - b1.z, t1.w - b1.w);
            } else {
                const float* pb = W + (size_t)(D + kr) * C + (gn - C);
                *(float4*)&Ws[wk][mb]     = *(const float4*)(pb);
                *(float4*)&Ws[wk][mb + 4] = *(const float4*)(pb + 4);
            }
        } else {
            for (int e = t; e < KT * 128; e += 256) {
                const int k = e >> 7, n = e & 127;
                const int gn = n0 + n, kr = k0 + k;
                Ws[k][wmap(n)] = (gn < C)
                    ? W[(size_t)kr * C + gn] - W[(size_t)(D + kr) * C + gn]
                    : W[(size_t)(D + kr) * C + (gn - C)];
            }
        }
        __syncthreads();

        const int mc = wmap(tx * 8);
        #pragma unroll
        for (int kk = 0; kk < KT; ++kk) {
            float xm[8], wn[8];
            *(float4*)&xm[0] = *(const float4*)&Xs[kk][ty * 8];
            *(float4*)&xm[4] = *(const float4*)&Xs[kk][ty * 8 + 4];
            *(float4*)&wn[0] = *(const float4*)&Ws[kk][mc];
            *(float4*)&wn[4] = *(const float4*)&Ws[kk][mc + 4];
            #pragma unroll
            for (int m = 0; m < 8; ++m)
                #pragma unroll
                for (int n = 0; n < 8; ++n)
                    acc[m][n] = fmaf(xm[m], wn[n], acc[m][n]);
        }
        __syncthreads();
    }

    // ---- epilogue: affine + route halves (8-col blocks never straddle C) ----
    const int gn = n0 + tx * 8;
    if (gn < C) {
        float fac[8];
        #pragma unroll
        for (int e = 0; e < 8; ++e) fac[e] = g[gn + e] * BN_SCALE_F;
        #pragma unroll
        for (int m = 0; m < 8; ++m) {
            float o[8];
            #pragma unroll
            for (int e = 0; e < 8; ++e) o[e] = fac[e] * acc[m][e];
            float* dst = A + (size_t)(m0 + ty * 8 + m) * C + gn;
            *(float4*)(dst)     = make_float4(o[0], o[1], o[2], o[3]);
            *(float4*)(dst + 4) = make_float4(o[4], o[5], o[6], o[7]);
        }
    } else {
        const int cb = gn - C;
        float fac[8], bb[8], bee[8];
        #pragma unroll
        for (int e = 0; e < 8; ++e) {
            fac[e] = g[cb + e] * BN_SCALE_F;
            bb[e]  = bias[cb + e];
            bee[e] = be[cb + e];
        }
        #pragma unroll
        for (int m = 0; m < 8; ++m) {
            float o[8];
            #pragma unroll
            for (int e = 0; e < 8; ++e)
                o[e] = fmaf(fac[e], acc[m][e] + bb[e], bee[e]);
            float* dst = Bv + (size_t)(m0 + ty * 8 + m) * C + cb;
            *(float4*)(dst)     = make_float4(o[0], o[1], o[2], o[3]);
            *(float4*)(dst + 4) = make_float4(o[4], o[5], o[6], o[7]);
        }
    }
}

// ---------------------------------------------------------------------------
// Combine: out[i][c] = relu(A[i][c] + max_{j in knn(i)} Bv[j][c]). out aliases A.
// ---------------------------------------------------------------------------
template<int C>
__global__ __launch_bounds__(C) void combine_kernel(
        const float* A, const float* __restrict__ Bv,
        const int* __restrict__ idx, float* out) {
    const int bi = blockIdx.x;
    const int c  = threadIdx.x;
    __shared__ int nbr[KNN];
    if (c < KNN) nbr[c] = idx[(size_t)bi * KNN + c];
    __syncthreads();
    const int b0 = bi & ~255;
    float mx = -INFINITY;
    #pragma unroll
    for (int kk = 0; kk < KNN; ++kk)
        mx = fmaxf(mx, Bv[(size_t)(b0 + nbr[kk]) * C + c]);
    float a = A[(size_t)bi * C + c];
    out[(size_t)bi * C + c] = fmaxf(a + mx, 0.f);
}

// ---------------------------------------------------------------------------
// Head: global max-pool over N, then 2 tiny FCs. One block per batch.
// ---------------------------------------------------------------------------
__global__ __launch_bounds__(256) void head_kernel(
        const float* __restrict__ h3, const float* __restrict__ Wf1,
        const float* __restrict__ bf1, const float* __restrict__ gf,
        const float* __restrict__ bef, const float* __restrict__ Wf2,
        const float* __restrict__ bf2, float* __restrict__ out) {
    const int b   = blockIdx.x;
    const int tid = threadIdx.x;
    __shared__ float p[256];
    __shared__ float f[128];
    const float* hb = h3 + (size_t)b * NPTS * 256;
    float mx = -INFINITY;
    for (int n = 0; n < NPTS; ++n) mx = fmaxf(mx, hb[(size_t)n * 256 + tid]);
    p[tid] = mx;
    __syncthreads();
    if (tid < 128) {
        float acc = bf1[tid];
        for (int d = 0; d < 256; ++d)
            acc = fmaf(p[d], Wf1[(size_t)d * 128 + tid], acc);
        float v = gf[tid] * (acc * BN_SCALE_F) + bef[tid];
        f[tid] = fmaxf(v, 0.f);
    }
    __syncthreads();
    if (tid < 12) {
        float acc = bf2[tid];
        for (int d = 0; d < 128; ++d)
            acc = fmaf(f[d], Wf2[(size_t)d * 12 + tid], acc);
        out[(size_t)b * 12 + tid] = acc;
    }
}

extern "C" void kernel_launch(void* const* d_in, const int* in_sizes, int n_in,
                              void* d_out, int out_size, void* d_ws, size_t ws_size,
                              hipStream_t stream) {
    const float* x   = (const float*)d_in[0];
    const float* W1  = (const float*)d_in[1];
    const float* b1  = (const float*)d_in[2];
    const float* g1  = (const float*)d_in[3];
    const float* be1 = (const float*)d_in[4];
    const float* W2  = (const float*)d_in[5];
    const float* b2  = (const float*)d_in[6];
    const float* g2  = (const float*)d_in[7];
    const float* be2 = (const float*)d_in[8];
    const float* W3  = (const float*)d_in[9];
    const float* b3  = (const float*)d_in[10];
    const float* g3  = (const float*)d_in[11];
    const float* be3 = (const float*)d_in[12];
    const float* Wf1 = (const float*)d_in[13];
    const float* bf1 = (const float*)d_in[14];
    const float* gf  = (const float*)d_in[15];
    const float* bef = (const float*)d_in[16];
    const float* Wf2 = (const float*)d_in[17];
    const float* bf2 = (const float*)d_in[18];
    float* out = (float*)d_out;

    char* ws = (char*)d_ws;
    const size_t idx_bytes = (size_t)NBATCH * NPTS * KNN * sizeof(int);   // 2 MB
    const size_t reg_bytes = (size_t)NBATCH * NPTS * 256 * sizeof(float); // 32 MB
    int*   idx = (int*)ws;
    float* R1  = (float*)(ws + idx_bytes);
    float* R2  = (float*)(ws + idx_bytes + reg_bytes);
    float* R3  = (float*)(ws + idx_bytes + 2 * reg_bytes);
    float* sqb = (float*)(ws + idx_bytes + 3 * reg_bytes);                // 128 KB

    const int BN = NBATCH * NPTS;        // 32768 points
    const int GRAM_GRID = NBATCH * 16;   // 2048 blocks of 256 threads
    const int TOPK_GRID = BN / 32;       // 1024 blocks
    const int MB = BN / 128;             // 256 m-blocks for the MLP GEMM

    // ---- Layer 1: x (D=6) -> h1 (C=64) in R1; d2 scratch = R3 ----
    sq_kernel<6><<<BN / 256, 256, 0, stream>>>(x, sqb);
    gram_kernel<6><<<GRAM_GRID, 256, 0, stream>>>(x, sqb, R3);
    topk_kernel<<<TOPK_GRID, 256, 0, stream>>>(R3, idx);
    mlp_gemm_kernel<6, 64><<<dim3(MB, 1), 256, 0, stream>>>(
        x, W1, b1, g1, be1, R1, R2);
    combine_kernel<64><<<BN, 64, 0, stream>>>(R1, R2, idx, R1);   // h1 = R1

    // ---- Layer 2: h1 (D=64) -> h2 (C=128) in R2; d2 scratch = R3 ----
    sq_kernel<64><<<BN / 256, 256, 0, stream>>>(R1, sqb);
    gram_kernel<64><<<GRAM_GRID, 256, 0, stream>>>(R1, sqb, R3);
    topk_kernel<<<TOPK_GRID, 256, 0, stream>>>(R3, idx);
    mlp_gemm_kernel<64, 128><<<dim3(MB, 2), 256, 0, stream>>>(
        R1, W2, b2, g2, be2, R2, R3);
    combine_kernel<128><<<BN, 128, 0, stream>>>(R2, R3, idx, R2); // h2 = R2

    // ---- Layer 3: h2 (D=128) -> h3 (C=256) in R3; d2 scratch = R1 ----
    sq_kernel<128><<<BN / 256, 256, 0, stream>>>(R2, sqb);
    gram_kernel<128><<<GRAM_GRID, 256, 0, stream>>>(R2, sqb, R1);
    topk_kernel<<<TOPK_GRID, 256, 0, stream>>>(R1, idx);
    mlp_gemm_kernel<128, 256><<<dim3(MB, 4), 256, 0, stream>>>(
        R2, W3, b3, g3, be3, R3, R1);
    combine_kernel<256><<<BN, 256, 0, stream>>>(R3, R1, idx, R3); // h3 = R3

    // ---- Head ----
    head_kernel<<<NBATCH, 256, 0, stream>>>(R3, Wf1, bf1, gf, bef, Wf2, bf2, out);
}

// Round 7
// 471.366 us; speedup vs baseline: 1.0951x; 1.0227x over previous
//
#include <hip/hip_runtime.h>
#include <cstdint>
#include <cstddef>

#define KNN 16
#define NPTS 256
#define NBATCH 128

static constexpr float BN_SCALE_F = 0.9999950000374997f; // 1/sqrt(1+1e-5)

__device__ inline unsigned int f32_ord(float f) {
    unsigned int u = __float_as_uint(f);
    return (u & 0x80000000u) ? ~u : (u | 0x80000000u);
}

// Ws column gap map: stride 160 (=0 mod 32); 16-blocks shifted by 4 banks.
__device__ __forceinline__ int wmap(int n) { return n + 4 * (n >> 4); }

// ---------------------------------------------------------------------------
// sq[t] = sum_d x[t][d]^2, sequential fmaf chain (matches reference assoc).
// ---------------------------------------------------------------------------
template<int D>
__global__ __launch_bounds__(256) void sq_kernel(const float* __restrict__ x,
                                                 float* __restrict__ sq) {
    const int t = blockIdx.x * 256 + threadIdx.x;
    const float* r = x + (size_t)t * D;
    float s = 0.f;
    #pragma unroll
    for (int d = 0; d < D; ++d) s = fmaf(r[d], r[d], s);
    sq[t] = s;
}

// ---------------------------------------------------------------------------
// Distance GEMM (unchanged from r6): d2 = (sq_i+sq_j) - 2*dot, diag=+INF.
// 64x64 tile / 256 threads, 4x4 per thread.
// ---------------------------------------------------------------------------
template<int D>
__global__ __launch_bounds__(256) void gram_kernel(const float* __restrict__ x,
                                                   const float* __restrict__ sq,
                                                   float* __restrict__ d2) {
    constexpr int KS = (D >= 16) ? 16 : D;
    const int t  = threadIdx.x;
    const int tx = t & 15, ty = t >> 4;
    const int b    = blockIdx.x >> 4;
    const int tile = blockIdx.x & 15;
    const int i0 = (tile & 3) * 64;
    const int j0 = (tile >> 2) * 64;
    const int base = b * NPTS;

    __shared__ float As[KS][68];
    __shared__ float Bs[KS][68];

    float acc[4][4] = {};
    for (int k0 = 0; k0 < D; k0 += KS) {
        if constexpr (D % 16 == 0) {
            const int r  = t >> 2;
            const int cq = (t & 3) * 4;
            const float4 va = *(const float4*)(x + (size_t)(base + i0 + r) * D + k0 + cq);
            const float4 vb = *(const float4*)(x + (size_t)(base + j0 + r) * D + k0 + cq);
            As[cq + 0][r] = va.x; As[cq + 1][r] = va.y;
            As[cq + 2][r] = va.z; As[cq + 3][r] = va.w;
            Bs[cq + 0][r] = vb.x; Bs[cq + 1][r] = vb.y;
            Bs[cq + 2][r] = vb.z; Bs[cq + 3][r] = vb.w;
        } else {
            for (int e = t; e < 64 * KS; e += 256) {
                const int r = e / KS, c = e % KS;
                As[c][r] = x[(size_t)(base + i0 + r) * D + k0 + c];
                Bs[c][r] = x[(size_t)(base + j0 + r) * D + k0 + c];
            }
        }
        __syncthreads();
        #pragma unroll
        for (int kk = 0; kk < KS; ++kk) {
            const float4 av = *(const float4*)&As[kk][ty * 4];
            const float4 bv = *(const float4*)&Bs[kk][tx * 4];
            const float am[4] = {av.x, av.y, av.z, av.w};
            const float bm[4] = {bv.x, bv.y, bv.z, bv.w};
            #pragma unroll
            for (int m = 0; m < 4; ++m)
                #pragma unroll
                for (int n = 0; n < 4; ++n)
                    acc[m][n] = fmaf(am[m], bm[n], acc[m][n]);
        }
        __syncthreads();
    }

    float sqi[4], sqj[4];
    #pragma unroll
    for (int m = 0; m < 4; ++m) {
        sqi[m] = sq[base + i0 + ty * 4 + m];
        sqj[m] = sq[base + j0 + tx * 4 + m];
    }
    #pragma unroll
    for (int m = 0; m < 4; ++m) {
        const int gi = i0 + ty * 4 + m;
        float v[4];
        #pragma unroll
        for (int n = 0; n < 4; ++n) {
            v[n] = (sqi[m] + sqj[n]) - 2.f * acc[m][n];
            if (gi == j0 + tx * 4 + n) v[n] = INFINITY;
        }
        float4* dst = (float4*)(d2 + ((size_t)b << 16) + (size_t)gi * NPTS + j0 + tx * 4);
        *dst = make_float4(v[0], v[1], v[2], v[3]);
    }
}

// ---------------------------------------------------------------------------
// Top-16 selection v3: u32 value/index pairs (gfx950 has no u64 compare —
// the u64-key ladder expanded to ~16 VALU/level; u32 pairs are ~6).
// Semantics identical to the bit-exact u64 version:
//  - strict < insertion keeps earlier-seen on equal values; j ascends per
//    thread and channels cover ascending j-ranges -> smaller-j tie-break.
//  - merge tournament scans channels ascending with strict < and advances
//    only the argmin channel (c == bc).
// Output order is irrelevant (combine takes a max over the 16).
// ---------------------------------------------------------------------------
__global__ __launch_bounds__(256) void topk_kernel(const float* __restrict__ d2,
                                                   int* __restrict__ idx) {
    const int t = threadIdx.x;
    const int p = t >> 3;          // local point 0..31
    const int q = t & 7;           // octant
    const int ig = blockIdx.x * 32 + p;
    const float* row = d2 + (size_t)ig * NPTS;

    unsigned int Lv[16], Li[16];
    #pragma unroll
    for (int r = 0; r < 16; ++r) { Lv[r] = 0xFFFFFFFFu; Li[r] = 0u; }

    const int jb = q * 32;
    #pragma unroll
    for (int jj = 0; jj < 32; jj += 4) {
        const float4 v4 = *(const float4*)(row + jb + jj);
        const float vv[4] = {v4.x, v4.y, v4.z, v4.w};
        #pragma unroll
        for (int e = 0; e < 4; ++e) {
            const unsigned int v = f32_ord(vv[e]);
            const unsigned int j = (unsigned int)(jb + jj + e);
            #pragma unroll
            for (int r = 15; r >= 1; --r) {
                const bool a = v < Lv[r];
                const bool b = v < Lv[r - 1];
                Lv[r] = a ? (b ? Lv[r - 1] : v) : Lv[r];
                Li[r] = a ? (b ? Li[r - 1] : j) : Li[r];
            }
            const bool a0 = v < Lv[0];
            Lv[0] = a0 ? v : Lv[0];
            Li[0] = a0 ? j : Li[0];
        }
    }

    __shared__ unsigned int   Kv[256][17];   // +1 pad
    __shared__ unsigned short Ki[256][18];   // +2 pad
    #pragma unroll
    for (int r = 0; r < 16; ++r) {
        Kv[t][r] = Lv[r];
        Ki[t][r] = (unsigned short)Li[r];
    }
    __syncthreads();

    if (t < 32) {
        const int pp  = t;
        const int igo = blockIdx.x * 32 + pp;
        unsigned int v[8], ii[8];
        int h[8];
        #pragma unroll
        for (int c = 0; c < 8; ++c) {
            h[c]  = 0;
            v[c]  = Kv[pp * 8 + c][0];
            ii[c] = Ki[pp * 8 + c][0];
        }
        int outj[16];
        #pragma unroll
        for (int r = 0; r < 16; ++r) {
            unsigned int bv = v[0], bi = ii[0];
            int bc = 0;
            #pragma unroll
            for (int c = 1; c < 8; ++c) {
                const bool tk = v[c] < bv;      // strict: lower c (lower j) wins ties
                bv = tk ? v[c]  : bv;
                bi = tk ? ii[c] : bi;
                bc = tk ? c     : bc;
            }
            outj[r] = (int)bi;
            #pragma unroll
            for (int c = 0; c < 8; ++c) {
                const bool hit = (c == bc);
                const int  hn  = h[c] + (hit ? 1 : 0);
                const unsigned int nv = Kv[pp * 8 + c][hn & 15];
                const unsigned int ni = Ki[pp * 8 + c][hn & 15];
                v[c]  = hit ? ((hn < 16) ? nv : 0xFFFFFFFFu) : v[c];
                ii[c] = hit ? ni : ii[c];
                h[c]  = hn;
            }
        }
        int4* op = (int4*)(idx + (size_t)igo * KNN);
        op[0] = make_int4(outj[0],  outj[1],  outj[2],  outj[3]);
        op[1] = make_int4(outj[4],  outj[5],  outj[6],  outj[7]);
        op[2] = make_int4(outj[8],  outj[9],  outj[10], outj[11]);
        op[3] = make_int4(outj[12], outj[13], outj[14], outj[15]);
    }
}

// ---------------------------------------------------------------------------
// Factorized edge-MLP GEMM (unchanged from r6).
// ---------------------------------------------------------------------------
template<int D, int C>
__global__ __launch_bounds__(256) void mlp_gemm_kernel(
        const float* __restrict__ x, const float* __restrict__ W,
        const float* __restrict__ bias, const float* __restrict__ g,
        const float* __restrict__ be,
        float* __restrict__ A, float* __restrict__ Bv) {
    constexpr int BM = 128;
    constexpr int KT = (D >= 16) ? 16 : D;
    const int t  = threadIdx.x;
    const int m0 = blockIdx.x * BM;
    const int n0 = blockIdx.y * 128;
    const int tx = t & 15;   // col group (8 cols)
    const int ty = t >> 4;   // row group (8 rows)

    __shared__ float Xs[KT][BM + 4];
    __shared__ float Ws[KT][160];      // gapped columns via wmap()

    float acc[8][8] = {};

    for (int k0 = 0; k0 < D; k0 += KT) {
        if constexpr (D % 16 == 0) {
            const int r  = t >> 1;          // 0..127
            const int cq = (t & 1) * 8;     // 0 or 8
            const float* src = x + (size_t)(m0 + r) * D + k0 + cq;
            const float4 v0 = *(const float4*)(src);
            const float4 v1 = *(const float4*)(src + 4);
            Xs[cq + 0][r] = v0.x; Xs[cq + 1][r] = v0.y;
            Xs[cq + 2][r] = v0.z; Xs[cq + 3][r] = v0.w;
            Xs[cq + 4][r] = v1.x; Xs[cq + 5][r] = v1.y;
            Xs[cq + 6][r] = v1.z; Xs[cq + 7][r] = v1.w;
        } else {
            for (int e = t; e < BM * KT; e += 256) {
                const int r = e / KT, c = e % KT;
                Xs[c][r] = x[(size_t)(m0 + r) * D + k0 + c];
            }
        }
        if constexpr (D % 16 == 0) {
            const int wk = t >> 4;           // 0..15 (k row)
            const int nq = (t & 15) * 8;     // col offset (8-block)
            const int mb = wmap(nq);         // mapped col base (contiguous 8)
            const int gn = n0 + nq;
            const int kr = k0 + wk;
            if (gn < C) {
                const float* pt = W + (size_t)kr * C + gn;
                const float* pb = W + (size_t)(D + kr) * C + gn;
                const float4 t0 = *(const float4*)(pt);
                const float4 t1 = *(const float4*)(pt + 4);
                const float4 b0 = *(const float4*)(pb);
                const float4 b1 = *(const float4*)(pb + 4);
                *(float4*)&Ws[wk][mb]     = make_float4(t0.x - b0.x, t0.y - b0.y,
                                                        t0.z - b0.z, t0.w - b0.w);
                *(float4*)&Ws[wk][mb + 4] = make_float4(t1.x - b1.x, t1.y - b1.y,
                                                        t1.z - b1.z, t1.w - b1.w);
            } else {
                const float* pb = W + (size_t)(D + kr) * C + (gn - C);
                *(float4*)&Ws[wk][mb]     = *(const float4*)(pb);
                *(float4*)&Ws[wk][mb + 4] = *(const float4*)(pb + 4);
            }
        } else {
            for (int e = t; e < KT * 128; e += 256) {
                const int k = e >> 7, n = e & 127;
                const int gn = n0 + n, kr = k0 + k;
                Ws[k][wmap(n)] = (gn < C)
                    ? W[(size_t)kr * C + gn] - W[(size_t)(D + kr) * C + gn]
                    : W[(size_t)(D + kr) * C + (gn - C)];
            }
        }
        __syncthreads();

        const int mc = wmap(tx * 8);
        #pragma unroll
        for (int kk = 0; kk < KT; ++kk) {
            float xm[8], wn[8];
            *(float4*)&xm[0] = *(const float4*)&Xs[kk][ty * 8];
            *(float4*)&xm[4] = *(const float4*)&Xs[kk][ty * 8 + 4];
            *(float4*)&wn[0] = *(const float4*)&Ws[kk][mc];
            *(float4*)&wn[4] = *(const float4*)&Ws[kk][mc + 4];
            #pragma unroll
            for (int m = 0; m < 8; ++m)
                #pragma unroll
                for (int n = 0; n < 8; ++n)
                    acc[m][n] = fmaf(xm[m], wn[n], acc[m][n]);
        }
        __syncthreads();
    }

    const int gn = n0 + tx * 8;
    if (gn < C) {
        float fac[8];
        #pragma unroll
        for (int e = 0; e < 8; ++e) fac[e] = g[gn + e] * BN_SCALE_F;
        #pragma unroll
        for (int m = 0; m < 8; ++m) {
            float o[8];
            #pragma unroll
            for (int e = 0; e < 8; ++e) o[e] = fac[e] * acc[m][e];
            float* dst = A + (size_t)(m0 + ty * 8 + m) * C + gn;
            *(float4*)(dst)     = make_float4(o[0], o[1], o[2], o[3]);
            *(float4*)(dst + 4) = make_float4(o[4], o[5], o[6], o[7]);
        }
    } else {
        const int cb = gn - C;
        float fac[8], bb[8], bee[8];
        #pragma unroll
        for (int e = 0; e < 8; ++e) {
            fac[e] = g[cb + e] * BN_SCALE_F;
            bb[e]  = bias[cb + e];
            bee[e] = be[cb + e];
        }
        #pragma unroll
        for (int m = 0; m < 8; ++m) {
            float o[8];
            #pragma unroll
            for (int e = 0; e < 8; ++e)
                o[e] = fmaf(fac[e], acc[m][e] + bb[e], bee[e]);
            float* dst = Bv + (size_t)(m0 + ty * 8 + m) * C + cb;
            *(float4*)(dst)     = make_float4(o[0], o[1], o[2], o[3]);
            *(float4*)(dst + 4) = make_float4(o[4], o[5], o[6], o[7]);
        }
    }
}

// ---------------------------------------------------------------------------
// Combine: out[i][c] = relu(A[i][c] + max_{j in knn(i)} Bv[j][c]). out aliases A.
// ---------------------------------------------------------------------------
template<int C>
__global__ __launch_bounds__(C) void combine_kernel(
        const float* A, const float* __restrict__ Bv,
        const int* __restrict__ idx, float* out) {
    const int bi = blockIdx.x;
    const int c  = threadIdx.x;
    __shared__ int nbr[KNN];
    if (c < KNN) nbr[c] = idx[(size_t)bi * KNN + c];
    __syncthreads();
    const int b0 = bi & ~255;
    float mx = -INFINITY;
    #pragma unroll
    for (int kk = 0; kk < KNN; ++kk)
        mx = fmaxf(mx, Bv[(size_t)(b0 + nbr[kk]) * C + c]);
    float a = A[(size_t)bi * C + c];
    out[(size_t)bi * C + c] = fmaxf(a + mx, 0.f);
}

// ---------------------------------------------------------------------------
// Head: global max-pool over N, then 2 tiny FCs. One block per batch.
// ---------------------------------------------------------------------------
__global__ __launch_bounds__(256) void head_kernel(
        const float* __restrict__ h3, const float* __restrict__ Wf1,
        const float* __restrict__ bf1, const float* __restrict__ gf,
        const float* __restrict__ bef, const float* __restrict__ Wf2,
        const float* __restrict__ bf2, float* __restrict__ out) {
    const int b   = blockIdx.x;
    const int tid = threadIdx.x;
    __shared__ float p[256];
    __shared__ float f[128];
    const float* hb = h3 + (size_t)b * NPTS * 256;
    float mx = -INFINITY;
    for (int n = 0; n < NPTS; ++n) mx = fmaxf(mx, hb[(size_t)n * 256 + tid]);
    p[tid] = mx;
    __syncthreads();
    if (tid < 128) {
        float acc = bf1[tid];
        for (int d = 0; d < 256; ++d)
            acc = fmaf(p[d], Wf1[(size_t)d * 128 + tid], acc);
        float v = gf[tid] * (acc * BN_SCALE_F) + bef[tid];
        f[tid] = fmaxf(v, 0.f);
    }
    __syncthreads();
    if (tid < 12) {
        float acc = bf2[tid];
        for (int d = 0; d < 128; ++d)
            acc = fmaf(f[d], Wf2[(size_t)d * 12 + tid], acc);
        out[(size_t)b * 12 + tid] = acc;
    }
}

extern "C" void kernel_launch(void* const* d_in, const int* in_sizes, int n_in,
                              void* d_out, int out_size, void* d_ws, size_t ws_size,
                              hipStream_t stream) {
    const float* x   = (const float*)d_in[0];
    const float* W1  = (const float*)d_in[1];
    const float* b1  = (const float*)d_in[2];
    const float* g1  = (const float*)d_in[3];
    const float* be1 = (const float*)d_in[4];
    const float* W2  = (const float*)d_in[5];
    const float* b2  = (const float*)d_in[6];
    const float* g2  = (const float*)d_in[7];
    const float* be2 = (const float*)d_in[8];
    const float* W3  = (const float*)d_in[9];
    const float* b3  = (const float*)d_in[10];
    const float* g3  = (const float*)d_in[11];
    const float* be3 = (const float*)d_in[12];
    const float* Wf1 = (const float*)d_in[13];
    const float* bf1 = (const float*)d_in[14];
    const float* gf  = (const float*)d_in[15];
    const float* bef = (const float*)d_in[16];
    const float* Wf2 = (const float*)d_in[17];
    const float* bf2 = (const float*)d_in[18];
    float* out = (float*)d_out;

    char* ws = (char*)d_ws;
    const size_t idx_bytes = (size_t)NBATCH * NPTS * KNN * sizeof(int);   // 2 MB
    const size_t reg_bytes = (size_t)NBATCH * NPTS * 256 * sizeof(float); // 32 MB
    int*   idx = (int*)ws;
    float* R1  = (float*)(ws + idx_bytes);
    float* R2  = (float*)(ws + idx_bytes + reg_bytes);
    float* R3  = (float*)(ws + idx_bytes + 2 * reg_bytes);
    float* sqb = (float*)(ws + idx_bytes + 3 * reg_bytes);                // 128 KB

    const int BN = NBATCH * NPTS;        // 32768 points
    const int GRAM_GRID = NBATCH * 16;   // 2048 blocks of 256 threads
    const int TOPK_GRID = BN / 32;       // 1024 blocks
    const int MB = BN / 128;             // 256 m-blocks for the MLP GEMM

    // ---- Layer 1: x (D=6) -> h1 (C=64) in R1; d2 scratch = R3 ----
    sq_kernel<6><<<BN / 256, 256, 0, stream>>>(x, sqb);
    gram_kernel<6><<<GRAM_GRID, 256, 0, stream>>>(x, sqb, R3);
    topk_kernel<<<TOPK_GRID, 256, 0, stream>>>(R3, idx);
    mlp_gemm_kernel<6, 64><<<dim3(MB, 1), 256, 0, stream>>>(
        x, W1, b1, g1, be1, R1, R2);
    combine_kernel<64><<<BN, 64, 0, stream>>>(R1, R2, idx, R1);   // h1 = R1

    // ---- Layer 2: h1 (D=64) -> h2 (C=128) in R2; d2 scratch = R3 ----
    sq_kernel<64><<<BN / 256, 256, 0, stream>>>(R1, sqb);
    gram_kernel<64><<<GRAM_GRID, 256, 0, stream>>>(R1, sqb, R3);
    topk_kernel<<<TOPK_GRID, 256, 0, stream>>>(R3, idx);
    mlp_gemm_kernel<64, 128><<<dim3(MB, 2), 256, 0, stream>>>(
        R1, W2, b2, g2, be2, R2, R3);
    combine_kernel<128><<<BN, 128, 0, stream>>>(R2, R3, idx, R2); // h2 = R2

    // ---- Layer 3: h2 (D=128) -> h3 (C=256) in R3; d2 scratch = R1 ----
    sq_kernel<128><<<BN / 256, 256, 0, stream>>>(R2, sqb);
    gram_kernel<128><<<GRAM_GRID, 256, 0, stream>>>(R2, sqb, R1);
    topk_kernel<<<TOPK_GRID, 256, 0, stream>>>(R1, idx);
    mlp_gemm_kernel<128, 256><<<dim3(MB, 4), 256, 0, stream>>>(
        R2, W3, b3, g3, be3, R3, R1);
    combine_kernel<256><<<BN, 256, 0, stream>>>(R3, R1, idx, R3); // h3 = R3

    // ---- Head ----
    head_kernel<<<NBATCH, 256, 0, stream>>>(R3, Wf1, bf1, gf, bef, Wf2, bf2, out);
}

// Round 8
// 463.284 us; speedup vs baseline: 1.1142x; 1.0174x over previous
//
#include <hip/hip_runtime.h>
#include <cstdint>
#include <cstddef>

#define KNN 16
#define NPTS 256
#define NBATCH 128

static constexpr float BN_SCALE_F = 0.9999950000374997f; // 1/sqrt(1+1e-5)

__device__ inline unsigned int f32_ord(float f) {
    unsigned int u = __float_as_uint(f);
    return (u & 0x80000000u) ? ~u : (u | 0x80000000u);
}

// Ws column gap map: stride 160 (=0 mod 32); 16-blocks shifted by 4 banks.
__device__ __forceinline__ int wmap(int n) { return n + 4 * (n >> 4); }

// ---------------------------------------------------------------------------
// sq[t] = sum_d x[t][d]^2, sequential fmaf chain (matches reference assoc).
// ---------------------------------------------------------------------------
template<int D>
__global__ __launch_bounds__(256) void sq_kernel(const float* __restrict__ x,
                                                 float* __restrict__ sq) {
    const int t = blockIdx.x * 256 + threadIdx.x;
    const float* r = x + (size_t)t * D;
    float s = 0.f;
    #pragma unroll
    for (int d = 0; d < D; ++d) s = fmaf(r[d], r[d], s);
    sq[t] = s;
}

// ---------------------------------------------------------------------------
// FUSED kNN: distance-GEMM tile (r6 gram, bit-identical d2) + in-LDS top-16
// (r7 u32 ladders). One block = 64 i-rows of one batch; j loops over four
// 64-wide tiles; d2 never goes to global memory.
//  gram roles: tx = t&15, ty = t>>4 (4x4 acc per thread, 64x64 tile)
//  select roles: sr = t>>2 (row 0..63), sc = t&3 (channel, 16 cands/tile)
// Selection = exact top-16 by (f32_ord(d2), j) lexicographic:
//  - per-thread insertion ladder, strict <, j scanned ascending
//  - 4-channel merge with explicit (value, index) tie-break
// ---------------------------------------------------------------------------
template<int D>
__global__ __launch_bounds__(256) void knn_fused_kernel(
        const float* __restrict__ x, const float* __restrict__ sq,
        int* __restrict__ idx) {
    constexpr int KS = (D >= 16) ? 16 : D;
    const int t  = threadIdx.x;
    const int tx = t & 15, ty = t >> 4;
    const int sr = t >> 2, sc = t & 3;
    const int b  = blockIdx.x >> 2;
    const int i0 = (blockIdx.x & 3) * 64;
    const int base = b * NPTS;

    __shared__ float As[KS][68];
    __shared__ float Bs[KS][68];
    __shared__ float d2L[64][65];            // also reused as merge values
    __shared__ unsigned short Mi[64][68];    // merge indices

    unsigned int Lv[16], Li[16];
    #pragma unroll
    for (int q = 0; q < 16; ++q) { Lv[q] = 0xFFFFFFFFu; Li[q] = 0u; }

    for (int jt = 0; jt < 4; ++jt) {
        const int j0 = jt * 64;
        float acc[4][4] = {};
        for (int k0 = 0; k0 < D; k0 += KS) {
            if constexpr (D % 16 == 0) {
                const int r  = t >> 2;
                const int cq = (t & 3) * 4;
                const float4 va = *(const float4*)(x + (size_t)(base + i0 + r) * D + k0 + cq);
                const float4 vb = *(const float4*)(x + (size_t)(base + j0 + r) * D + k0 + cq);
                As[cq + 0][r] = va.x; As[cq + 1][r] = va.y;
                As[cq + 2][r] = va.z; As[cq + 3][r] = va.w;
                Bs[cq + 0][r] = vb.x; Bs[cq + 1][r] = vb.y;
                Bs[cq + 2][r] = vb.z; Bs[cq + 3][r] = vb.w;
            } else {
                for (int e = t; e < 64 * KS; e += 256) {
                    const int r = e / KS, c = e % KS;
                    As[c][r] = x[(size_t)(base + i0 + r) * D + k0 + c];
                    Bs[c][r] = x[(size_t)(base + j0 + r) * D + k0 + c];
                }
            }
            __syncthreads();
            #pragma unroll
            for (int kk = 0; kk < KS; ++kk) {
                const float4 av = *(const float4*)&As[kk][ty * 4];
                const float4 bv = *(const float4*)&Bs[kk][tx * 4];
                const float am[4] = {av.x, av.y, av.z, av.w};
                const float bm[4] = {bv.x, bv.y, bv.z, bv.w};
                #pragma unroll
                for (int m = 0; m < 4; ++m)
                    #pragma unroll
                    for (int n = 0; n < 4; ++n)
                        acc[m][n] = fmaf(am[m], bm[n], acc[m][n]);
            }
            __syncthreads();
        }

        // ---- epilogue: d2 tile into LDS (same arithmetic as r6 gram) ----
        float sqi[4], sqj[4];
        #pragma unroll
        for (int m = 0; m < 4; ++m) {
            sqi[m] = sq[base + i0 + ty * 4 + m];
            sqj[m] = sq[base + j0 + tx * 4 + m];
        }
        #pragma unroll
        for (int m = 0; m < 4; ++m) {
            const int gi = i0 + ty * 4 + m;
            #pragma unroll
            for (int n = 0; n < 4; ++n) {
                float v = (sqi[m] + sqj[n]) - 2.f * acc[m][n];
                if (gi == j0 + tx * 4 + n) v = INFINITY;
                d2L[ty * 4 + m][tx * 4 + n] = v;
            }
        }
        __syncthreads();

        // ---- insertion: thread (sr, sc) takes cands j = j0 + sc*16 + i ----
        #pragma unroll
        for (int i = 0; i < 16; ++i) {
            const unsigned int v = f32_ord(d2L[sr][sc * 16 + i]);
            const unsigned int j = (unsigned int)(j0 + sc * 16 + i);
            #pragma unroll
            for (int q = 15; q >= 1; --q) {
                const bool a = v < Lv[q];
                const bool c = v < Lv[q - 1];
                Lv[q] = a ? (c ? Lv[q - 1] : v) : Lv[q];
                Li[q] = a ? (c ? Li[q - 1] : j) : Li[q];
            }
            const bool a0 = v < Lv[0];
            Lv[0] = a0 ? v : Lv[0];
            Li[0] = a0 ? j : Li[0];
        }
        // no trailing sync needed: next tile's d2L writes are fenced by the
        // k-loop's two __syncthreads() before the epilogue.
    }

    __syncthreads();   // all insertions done before d2L is reused for merge
    #pragma unroll
    for (int q = 0; q < 16; ++q) {
        d2L[sr][sc * 16 + q] = __uint_as_float(Lv[q]);
        Mi[sr][sc * 16 + q]  = (unsigned short)Li[q];
    }
    __syncthreads();

    if (t < 64) {
        const int row = t;
        int h[4];
        unsigned int cv[4], ci[4];
        #pragma unroll
        for (int c = 0; c < 4; ++c) {
            h[c]  = 0;
            cv[c] = __float_as_uint(d2L[row][c * 16]);
            ci[c] = Mi[row][c * 16];
        }
        int outj[16];
        #pragma unroll
        for (int rd = 0; rd < 16; ++rd) {
            unsigned int bv = cv[0], bi = ci[0];
            int bc = 0;
            #pragma unroll
            for (int c = 1; c < 4; ++c) {
                const bool tk = (cv[c] < bv) | ((cv[c] == bv) & (ci[c] < bi));
                bv = tk ? cv[c] : bv;
                bi = tk ? ci[c] : bi;
                bc = tk ? c     : bc;
            }
            outj[rd] = (int)bi;
            #pragma unroll
            for (int c = 0; c < 4; ++c) {
                if (c == bc) {
                    const int hn = h[c] + 1;
                    h[c] = hn;
                    if (hn < 16) {
                        cv[c] = __float_as_uint(d2L[row][c * 16 + hn]);
                        ci[c] = Mi[row][c * 16 + hn];
                    } else {
                        cv[c] = 0xFFFFFFFFu;
                    }
                }
            }
        }
        int4* op = (int4*)(idx + (size_t)(base + i0 + row) * KNN);
        op[0] = make_int4(outj[0],  outj[1],  outj[2],  outj[3]);
        op[1] = make_int4(outj[4],  outj[5],  outj[6],  outj[7]);
        op[2] = make_int4(outj[8],  outj[9],  outj[10], outj[11]);
        op[3] = make_int4(outj[12], outj[13], outj[14], outj[15]);
    }
}

// ---------------------------------------------------------------------------
// Factorized edge-MLP GEMM (unchanged from r6/r7).
// ---------------------------------------------------------------------------
template<int D, int C>
__global__ __launch_bounds__(256) void mlp_gemm_kernel(
        const float* __restrict__ x, const float* __restrict__ W,
        const float* __restrict__ bias, const float* __restrict__ g,
        const float* __restrict__ be,
        float* __restrict__ A, float* __restrict__ Bv) {
    constexpr int BM = 128;
    constexpr int KT = (D >= 16) ? 16 : D;
    const int t  = threadIdx.x;
    const int m0 = blockIdx.x * BM;
    const int n0 = blockIdx.y * 128;
    const int tx = t & 15;   // col group (8 cols)
    const int ty = t >> 4;   // row group (8 rows)

    __shared__ float Xs[KT][BM + 4];
    __shared__ float Ws[KT][160];      // gapped columns via wmap()

    float acc[8][8] = {};

    for (int k0 = 0; k0 < D; k0 += KT) {
        if constexpr (D % 16 == 0) {
            const int r  = t >> 1;          // 0..127
            const int cq = (t & 1) * 8;     // 0 or 8
            const float* src = x + (size_t)(m0 + r) * D + k0 + cq;
            const float4 v0 = *(const float4*)(src);
            const float4 v1 = *(const float4*)(src + 4);
            Xs[cq + 0][r] = v0.x; Xs[cq + 1][r] = v0.y;
            Xs[cq + 2][r] = v0.z; Xs[cq + 3][r] = v0.w;
            Xs[cq + 4][r] = v1.x; Xs[cq + 5][r] = v1.y;
            Xs[cq + 6][r] = v1.z; Xs[cq + 7][r] = v1.w;
        } else {
            for (int e = t; e < BM * KT; e += 256) {
                const int r = e / KT, c = e % KT;
                Xs[c][r] = x[(size_t)(m0 + r) * D + k0 + c];
            }
        }
        if constexpr (D % 16 == 0) {
            const int wk = t >> 4;           // 0..15 (k row)
            const int nq = (t & 15) * 8;     // col offset (8-block)
            const int mb = wmap(nq);         // mapped col base (contiguous 8)
            const int gn = n0 + nq;
            const int kr = k0 + wk;
            if (gn < C) {
                const float* pt = W + (size_t)kr * C + gn;
                const float* pb = W + (size_t)(D + kr) * C + gn;
                const float4 t0 = *(const float4*)(pt);
                const float4 t1 = *(const float4*)(pt + 4);
                const float4 b0 = *(const float4*)(pb);
                const float4 b1 = *(const float4*)(pb + 4);
                *(float4*)&Ws[wk][mb]     = make_float4(t0.x - b0.x, t0.y - b0.y,
                                                        t0.z - b0.z, t0.w - b0.w);
                *(float4*)&Ws[wk][mb + 4] = make_float4(t1.x - b1.x, t1.y - b1.y,
                                                        t1.z - b1.z, t1.w - b1.w);
            } else {
                const float* pb = W + (size_t)(D + kr) * C + (gn - C);
                *(float4*)&Ws[wk][mb]     = *(const float4*)(pb);
                *(float4*)&Ws[wk][mb + 4] = *(const float4*)(pb + 4);
            }
        } else {
            for (int e = t; e < KT * 128; e += 256) {
                const int k = e >> 7, n = e & 127;
                const int gn = n0 + n, kr = k0 + k;
                Ws[k][wmap(n)] = (gn < C)
                    ? W[(size_t)kr * C + gn] - W[(size_t)(D + kr) * C + gn]
                    : W[(size_t)(D + kr) * C + (gn - C)];
            }
        }
        __syncthreads();

        const int mc = wmap(tx * 8);
        #pragma unroll
        for (int kk = 0; kk < KT; ++kk) {
            float xm[8], wn[8];
            *(float4*)&xm[0] = *(const float4*)&Xs[kk][ty * 8];
            *(float4*)&xm[4] = *(const float4*)&Xs[kk][ty * 8 + 4];
            *(float4*)&wn[0] = *(const float4*)&Ws[kk][mc];
            *(float4*)&wn[4] = *(const float4*)&Ws[kk][mc + 4];
            #pragma unroll
            for (int m = 0; m < 8; ++m)
                #pragma unroll
                for (int n = 0; n < 8; ++n)
                    acc[m][n] = fmaf(xm[m], wn[n], acc[m][n]);
        }
        __syncthreads();
    }

    const int gn = n0 + tx * 8;
    if (gn < C) {
        float fac[8];
        #pragma unroll
        for (int e = 0; e < 8; ++e) fac[e] = g[gn + e] * BN_SCALE_F;
        #pragma unroll
        for (int m = 0; m < 8; ++m) {
            float o[8];
            #pragma unroll
            for (int e = 0; e < 8; ++e) o[e] = fac[e] * acc[m][e];
            float* dst = A + (size_t)(m0 + ty * 8 + m) * C + gn;
            *(float4*)(dst)     = make_float4(o[0], o[1], o[2], o[3]);
            *(float4*)(dst + 4) = make_float4(o[4], o[5], o[6], o[7]);
        }
    } else {
        const int cb = gn - C;
        float fac[8], bb[8], bee[8];
        #pragma unroll
        for (int e = 0; e < 8; ++e) {
            fac[e] = g[cb + e] * BN_SCALE_F;
            bb[e]  = bias[cb + e];
            bee[e] = be[cb + e];
        }
        #pragma unroll
        for (int m = 0; m < 8; ++m) {
            float o[8];
            #pragma unroll
            for (int e = 0; e < 8; ++e)
                o[e] = fmaf(fac[e], acc[m][e] + bb[e], bee[e]);
            float* dst = Bv + (size_t)(m0 + ty * 8 + m) * C + cb;
            *(float4*)(dst)     = make_float4(o[0], o[1], o[2], o[3]);
            *(float4*)(dst + 4) = make_float4(o[4], o[5], o[6], o[7]);
        }
    }
}

// ---------------------------------------------------------------------------
// Combine: out[i][c] = relu(A[i][c] + max_{j in knn(i)} Bv[j][c]). out aliases A.
// ---------------------------------------------------------------------------
template<int C>
__global__ __launch_bounds__(C) void combine_kernel(
        const float* A, const float* __restrict__ Bv,
        const int* __restrict__ idx, float* out) {
    const int bi = blockIdx.x;
    const int c  = threadIdx.x;
    __shared__ int nbr[KNN];
    if (c < KNN) nbr[c] = idx[(size_t)bi * KNN + c];
    __syncthreads();
    const int b0 = bi & ~255;
    float mx = -INFINITY;
    #pragma unroll
    for (int kk = 0; kk < KNN; ++kk)
        mx = fmaxf(mx, Bv[(size_t)(b0 + nbr[kk]) * C + c]);
    float a = A[(size_t)bi * C + c];
    out[(size_t)bi * C + c] = fmaxf(a + mx, 0.f);
}

// ---------------------------------------------------------------------------
// Head: global max-pool over N, then 2 tiny FCs. One block per batch.
// ---------------------------------------------------------------------------
__global__ __launch_bounds__(256) void head_kernel(
        const float* __restrict__ h3, const float* __restrict__ Wf1,
        const float* __restrict__ bf1, const float* __restrict__ gf,
        const float* __restrict__ bef, const float* __restrict__ Wf2,
        const float* __restrict__ bf2, float* __restrict__ out) {
    const int b   = blockIdx.x;
    const int tid = threadIdx.x;
    __shared__ float p[256];
    __shared__ float f[128];
    const float* hb = h3 + (size_t)b * NPTS * 256;
    float mx = -INFINITY;
    for (int n = 0; n < NPTS; ++n) mx = fmaxf(mx, hb[(size_t)n * 256 + tid]);
    p[tid] = mx;
    __syncthreads();
    if (tid < 128) {
        float acc = bf1[tid];
        for (int d = 0; d < 256; ++d)
            acc = fmaf(p[d], Wf1[(size_t)d * 128 + tid], acc);
        float v = gf[tid] * (acc * BN_SCALE_F) + bef[tid];
        f[tid] = fmaxf(v, 0.f);
    }
    __syncthreads();
    if (tid < 12) {
        float acc = bf2[tid];
        for (int d = 0; d < 128; ++d)
            acc = fmaf(f[d], Wf2[(size_t)d * 12 + tid], acc);
        out[(size_t)b * 12 + tid] = acc;
    }
}

extern "C" void kernel_launch(void* const* d_in, const int* in_sizes, int n_in,
                              void* d_out, int out_size, void* d_ws, size_t ws_size,
                              hipStream_t stream) {
    const float* x   = (const float*)d_in[0];
    const float* W1  = (const float*)d_in[1];
    const float* b1  = (const float*)d_in[2];
    const float* g1  = (const float*)d_in[3];
    const float* be1 = (const float*)d_in[4];
    const float* W2  = (const float*)d_in[5];
    const float* b2  = (const float*)d_in[6];
    const float* g2  = (const float*)d_in[7];
    const float* be2 = (const float*)d_in[8];
    const float* W3  = (const float*)d_in[9];
    const float* b3  = (const float*)d_in[10];
    const float* g3  = (const float*)d_in[11];
    const float* be3 = (const float*)d_in[12];
    const float* Wf1 = (const float*)d_in[13];
    const float* bf1 = (const float*)d_in[14];
    const float* gf  = (const float*)d_in[15];
    const float* bef = (const float*)d_in[16];
    const float* Wf2 = (const float*)d_in[17];
    const float* bf2 = (const float*)d_in[18];
    float* out = (float*)d_out;

    char* ws = (char*)d_ws;
    const size_t idx_bytes = (size_t)NBATCH * NPTS * KNN * sizeof(int);   // 2 MB
    const size_t reg_bytes = (size_t)NBATCH * NPTS * 256 * sizeof(float); // 32 MB
    int*   idx = (int*)ws;
    float* R1  = (float*)(ws + idx_bytes);
    float* R2  = (float*)(ws + idx_bytes + reg_bytes);
    float* R3  = (float*)(ws + idx_bytes + 2 * reg_bytes);
    float* sqb = (float*)(ws + idx_bytes + 3 * reg_bytes);                // 128 KB

    const int BN = NBATCH * NPTS;        // 32768 points
    const int KNN_GRID = NBATCH * 4;     // 512 blocks (64 i-rows each)
    const int MB = BN / 128;             // 256 m-blocks for the MLP GEMM

    // ---- Layer 1: x (D=6) -> h1 (C=64) in R1 ----
    sq_kernel<6><<<BN / 256, 256, 0, stream>>>(x, sqb);
    knn_fused_kernel<6><<<KNN_GRID, 256, 0, stream>>>(x, sqb, idx);
    mlp_gemm_kernel<6, 64><<<dim3(MB, 1), 256, 0, stream>>>(
        x, W1, b1, g1, be1, R1, R2);
    combine_kernel<64><<<BN, 64, 0, stream>>>(R1, R2, idx, R1);   // h1 = R1

    // ---- Layer 2: h1 (D=64) -> h2 (C=128) in R2 ----
    sq_kernel<64><<<BN / 256, 256, 0, stream>>>(R1, sqb);
    knn_fused_kernel<64><<<KNN_GRID, 256, 0, stream>>>(R1, sqb, idx);
    mlp_gemm_kernel<64, 128><<<dim3(MB, 2), 256, 0, stream>>>(
        R1, W2, b2, g2, be2, R2, R3);
    combine_kernel<128><<<BN, 128, 0, stream>>>(R2, R3, idx, R2); // h2 = R2

    // ---- Layer 3: h2 (D=128) -> h3 (C=256) in R3 ----
    sq_kernel<128><<<BN / 256, 256, 0, stream>>>(R2, sqb);
    knn_fused_kernel<128><<<KNN_GRID, 256, 0, stream>>>(R2, sqb, idx);
    mlp_gemm_kernel<128, 256><<<dim3(MB, 4), 256, 0, stream>>>(
        R2, W3, b3, g3, be3, R3, R1);
    combine_kernel<256><<<BN, 256, 0, stream>>>(R3, R1, idx, R3); // h3 = R3

    // ---- Head ----
    head_kernel<<<NBATCH, 256, 0, stream>>>(R3, Wf1, bf1, gf, bef, Wf2, bf2, out);
}